// Round 6
// baseline (391.191 us; speedup 1.0000x reference)
//
#include <hip/hip_runtime.h>

#define N_BATCH 8192
#define S 14
#define N_CELLS (N_BATCH * S * S)     // 1,605,632 cells
#define N_PAIRS (N_CELLS / 2)         // 802,816 pairs (2 cells = 60 floats = 240B)
#define BLOCK 256
#define GRID (N_PAIRS / BLOCK)        // 3136 blocks, exactly one pair per lane
#define NT_START 1960                 // blocks >= this: non-temporal (streaming) slice
                                      // resident slice = 62.5% x 385MB = 241MB < 256MB L3

typedef float f32x4 __attribute__((ext_vector_type(4)));

// r4 winner (pinned 30-deep float4 burst, 3.04 TB/s delivered) + two byte/latency
// levers:
//  1. skip tv[9] (target floats 36..39 = cell B's t[6..9]): fully dead 16B chunk
//     once T[9] is replaced by the identity t[9]==t[4] (target=concat([box,box,cls]),
//     so both conf slots hold obj). -3.3% total traffic.
//  2. nt residency shaping: the 385MB sweep thrashes the 256MB L3 (188MB HBM fetch
//     vs 129MB at optimal replacement). Fixed address split: blocks < NT_START are
//     normal (stay L3-resident), blocks >= NT_START load non-temporal (evict-first,
//     stream from HBM). Converges hits onto a stable 241MB set -> fewer HBM bytes,
//     lower average latency under the per-CU miss-concurrency budget.
__global__ __launch_bounds__(BLOCK) void yolo_loss_kernel(
    const float* __restrict__ pred, const float* __restrict__ targ,
    float* __restrict__ out)
{
    const int pair = blockIdx.x * BLOCK + (int)threadIdx.x;

    const f32x4* p4 = reinterpret_cast<const f32x4*>(pred) + (size_t)pair * 15;
    const f32x4* t4 = reinterpret_cast<const f32x4*>(targ) + (size_t)pair * 15;

    f32x4 pv[15], tv[15];
    if (blockIdx.x >= NT_START) {   // block-uniform branch, no divergence
#pragma unroll
        for (int c = 0; c < 15; ++c) pv[c] = __builtin_nontemporal_load(p4 + c);
#pragma unroll
        for (int c = 0; c < 15; ++c)
            if (c != 9) tv[c] = __builtin_nontemporal_load(t4 + c);
    } else {
#pragma unroll
        for (int c = 0; c < 15; ++c) pv[c] = p4[c];
#pragma unroll
        for (int c = 0; c < 15; ++c)
            if (c != 9) tv[c] = t4[c];
    }

    // Hard pin (r3 lesson: only a data dependence forces the burst): all 29
    // loaded float4s must be live in VGPRs here -> 29-deep MLP before compute.
    asm volatile(""
        :
        : "v"(pv[0]), "v"(pv[1]), "v"(pv[2]), "v"(pv[3]), "v"(pv[4]),
          "v"(pv[5]), "v"(pv[6]), "v"(pv[7]), "v"(pv[8]), "v"(pv[9]),
          "v"(pv[10]), "v"(pv[11]), "v"(pv[12]), "v"(pv[13]), "v"(pv[14]),
          "v"(tv[0]), "v"(tv[1]), "v"(tv[2]), "v"(tv[3]), "v"(tv[4]),
          "v"(tv[5]), "v"(tv[6]), "v"(tv[7]), "v"(tv[8]),
          "v"(tv[10]), "v"(tv[11]), "v"(tv[12]), "v"(tv[13]), "v"(tv[14]));

    float p[60], t[60];
#pragma unroll
    for (int c = 0; c < 15; ++c) {
        p[4 * c + 0] = pv[c][0]; p[4 * c + 1] = pv[c][1];
        p[4 * c + 2] = pv[c][2]; p[4 * c + 3] = pv[c][3];
    }
#pragma unroll
    for (int c = 0; c < 15; ++c) {
        if (c == 9) continue;   // t[36..39] never read (T[9] -> T[4] identity)
        t[4 * c + 0] = tv[c][0]; t[4 * c + 1] = tv[c][1];
        t[4 * c + 2] = tv[c][2]; t[4 * c + 3] = tv[c][3];
    }

    const float INV14 = 1.0f / 14.0f;
    float acc = 0.0f;

#pragma unroll
    for (int cell = 0; cell < 2; ++cell) {
        const float* P = p + 30 * cell;
        const float* T = t + 30 * cell;

        const float objf = (T[4] > 0.0f) ? 1.0f : 0.0f;
        const float noof = 1.0f - objf;

        // no-object conf loss (indices 4, 9). T[9]==T[4] (target boxes duplicated).
        const float d4 = P[4] - T[4];
        const float d9 = P[9] - T[4];
        const float nooobj = noof * (d4 * d4 + d9 * d9);

        // target box (t[5..9] unused/duplicate)
        const float tx = T[0] * INV14, ty = T[1] * INV14;
        const float tw = T[2], th = T[3];
        const float tx1 = tx - 0.5f * tw, ty1 = ty - 0.5f * th;
        const float tx2 = tx + 0.5f * tw, ty2 = ty + 0.5f * th;
        const float area_t = (tx2 - tx1) * (ty2 - ty1);

        float iou[2];
#pragma unroll
        for (int b = 0; b < 2; ++b) {
            const float px = P[5 * b + 0] * INV14, py = P[5 * b + 1] * INV14;
            const float pw = P[5 * b + 2], ph = P[5 * b + 3];
            const float px1 = px - 0.5f * pw, py1 = py - 0.5f * ph;
            const float px2 = px + 0.5f * pw, py2 = py + 0.5f * ph;
            const float ltx = fmaxf(px1, tx1), lty = fmaxf(py1, ty1);
            const float rbx = fminf(px2, tx2), rby = fminf(py2, ty2);
            const float wx = fmaxf(rbx - ltx, 0.0f);
            const float wy = fmaxf(rby - lty, 0.0f);
            const float inter = wx * wy;
            const float area_p = (px2 - px1) * (py2 - py1);
            iou[b] = inter / (area_p + area_t - inter);
        }

        // responsible box: jnp.argmax -> ties pick box 0
        const bool r1 = (iou[1] > iou[0]);
        const float max_iou = fmaxf(iou[0], iou[1]);

        const float pc  = r1 ? P[9] : P[4];
        const float pnc = r1 ? P[4] : P[9];
        const float contain = objf * (pc - max_iou) * (pc - max_iou);
        const float not_contain = objf * pnc * pnc;

        const float rx = r1 ? P[5] : P[0];
        const float ry = r1 ? P[6] : P[1];
        const float rw = r1 ? P[7] : P[2];
        const float rh = r1 ? P[8] : P[3];
        const float dx = rx - T[0];
        const float dy = ry - T[1];
        const float dw = sqrtf(rw) - sqrtf(T[2]);
        const float dh = sqrtf(rh) - sqrtf(T[3]);
        const float loc = objf * (dx * dx + dy * dy + dw * dw + dh * dh);

        float cls = 0.0f;
#pragma unroll
        for (int k = 10; k < 30; ++k) {
            const float d = P[k] - T[k];
            cls += d * d;
        }
        cls *= objf;

        acc += 5.0f * loc + 2.0f * contain + 0.5f * nooobj + cls + not_contain;
    }

    acc *= (1.0f / (float)N_BATCH);

    // wave reduction, then 4-wave block reduction -> one atomic per block
#pragma unroll
    for (int off = 32; off > 0; off >>= 1)
        acc += __shfl_down(acc, off, 64);

    __shared__ float wsum[BLOCK / 64];
    const int lane = threadIdx.x & 63;
    const int wid = (int)threadIdx.x >> 6;
    if (lane == 0) wsum[wid] = acc;
    __syncthreads();
    if (threadIdx.x == 0)
        atomicAdd(out, wsum[0] + wsum[1] + wsum[2] + wsum[3]);
}

extern "C" void kernel_launch(void* const* d_in, const int* in_sizes, int n_in,
                              void* d_out, int out_size, void* d_ws, size_t ws_size,
                              hipStream_t stream) {
    const float* pred = (const float*)d_in[0];
    const float* targ = (const float*)d_in[1];
    float* out = (float*)d_out;

    hipMemsetAsync(out, 0, sizeof(float), stream);

    yolo_loss_kernel<<<GRID, BLOCK, 0, stream>>>(pred, targ, out);
}

// Round 7
// 374.340 us; speedup vs baseline: 1.0450x; 1.0450x over previous
//
#include <hip/hip_runtime.h>

#define N_BATCH 8192
#define S 14
#define N_CELLS (N_BATCH * S * S)     // 1,605,632 cells
#define N_PAIRS (N_CELLS / 2)         // 802,816 pairs (2 cells = 60 floats = 240B)
#define BLOCK 256
#define GRID (N_PAIRS / BLOCK)        // 3136 blocks, exactly one pair per lane

typedef float f32x4 __attribute__((ext_vector_type(4)));

// FINAL: revert to the round-4 optimum (126.7 us kernel, 3.04 TB/s delivered =
// 97% of the chip's measured per-direction read rate; m13 copy reads at
// 5.1 B/cy/CU, this kernel at 4.95).
// Tested and rejected: nt residency shaping (r6: FETCH 190->338MB, delivered
// DROPPED to 2.67 TB/s), dword-level byte skipping (r6: HBM is line-granular,
// every 64B line contains used bytes -> zero traffic saved), coalesced LDS-DMA
// (r5: 2.85 TB/s), higher occupancy (r1: 52% occ, 2.83 TB/s). Delivered read
// rate is pinned at ~3 TB/s across every structure -> chip-level read-return
// cap, and this kernel sits on it.
//
// Structure: each lane owns TWO adjacent cells (240B = 15 aligned float4 per
// tensor). The asm with 30 "v" float4 inputs creates a hard data dependence
// forcing all 30 global_load_dwordx4 to issue before compute (without it LLVM
// sinks loads to first use -> VGPR=36, L1 thrash, FETCH 456MB > app bytes).
__global__ __launch_bounds__(BLOCK) void yolo_loss_kernel(
    const float* __restrict__ pred, const float* __restrict__ targ,
    float* __restrict__ out)
{
    const int pair = blockIdx.x * BLOCK + (int)threadIdx.x;

    const f32x4* p4 = reinterpret_cast<const f32x4*>(pred) + (size_t)pair * 15;
    const f32x4* t4 = reinterpret_cast<const f32x4*>(targ) + (size_t)pair * 15;

    f32x4 pv[15], tv[15];
#pragma unroll
    for (int c = 0; c < 15; ++c) pv[c] = p4[c];
#pragma unroll
    for (int c = 0; c < 15; ++c) tv[c] = t4[c];

    // Hard pin: every loaded value must be materialized in VGPRs HERE.
    asm volatile(""
        :
        : "v"(pv[0]), "v"(pv[1]), "v"(pv[2]), "v"(pv[3]), "v"(pv[4]),
          "v"(pv[5]), "v"(pv[6]), "v"(pv[7]), "v"(pv[8]), "v"(pv[9]),
          "v"(pv[10]), "v"(pv[11]), "v"(pv[12]), "v"(pv[13]), "v"(pv[14]),
          "v"(tv[0]), "v"(tv[1]), "v"(tv[2]), "v"(tv[3]), "v"(tv[4]),
          "v"(tv[5]), "v"(tv[6]), "v"(tv[7]), "v"(tv[8]), "v"(tv[9]),
          "v"(tv[10]), "v"(tv[11]), "v"(tv[12]), "v"(tv[13]), "v"(tv[14]));

    float p[60], t[60];
#pragma unroll
    for (int c = 0; c < 15; ++c) {
        p[4 * c + 0] = pv[c][0]; p[4 * c + 1] = pv[c][1];
        p[4 * c + 2] = pv[c][2]; p[4 * c + 3] = pv[c][3];
        t[4 * c + 0] = tv[c][0]; t[4 * c + 1] = tv[c][1];
        t[4 * c + 2] = tv[c][2]; t[4 * c + 3] = tv[c][3];
    }

    const float INV14 = 1.0f / 14.0f;
    float acc = 0.0f;

#pragma unroll
    for (int cell = 0; cell < 2; ++cell) {
        const float* P = p + 30 * cell;
        const float* T = t + 30 * cell;

        const float objf = (T[4] > 0.0f) ? 1.0f : 0.0f;
        const float noof = 1.0f - objf;

        // no-object confidence loss (conf indices 4, 9)
        const float d4 = P[4] - T[4];
        const float d9 = P[9] - T[9];
        const float nooobj = noof * (d4 * d4 + d9 * d9);

        // target box (target boxes duplicated; t[5..8] unused by reference)
        const float tx = T[0] * INV14, ty = T[1] * INV14;
        const float tw = T[2], th = T[3];
        const float tx1 = tx - 0.5f * tw, ty1 = ty - 0.5f * th;
        const float tx2 = tx + 0.5f * tw, ty2 = ty + 0.5f * th;
        const float area_t = (tx2 - tx1) * (ty2 - ty1);

        float iou[2];
#pragma unroll
        for (int b = 0; b < 2; ++b) {
            const float px = P[5 * b + 0] * INV14, py = P[5 * b + 1] * INV14;
            const float pw = P[5 * b + 2], ph = P[5 * b + 3];
            const float px1 = px - 0.5f * pw, py1 = py - 0.5f * ph;
            const float px2 = px + 0.5f * pw, py2 = py + 0.5f * ph;
            const float ltx = fmaxf(px1, tx1), lty = fmaxf(py1, ty1);
            const float rbx = fminf(px2, tx2), rby = fminf(py2, ty2);
            const float wx = fmaxf(rbx - ltx, 0.0f);
            const float wy = fmaxf(rby - lty, 0.0f);
            const float inter = wx * wy;
            const float area_p = (px2 - px1) * (py2 - py1);
            iou[b] = inter / (area_p + area_t - inter);
        }

        // responsible box: jnp.argmax -> ties pick box 0
        const bool r1 = (iou[1] > iou[0]);
        const float max_iou = fmaxf(iou[0], iou[1]);

        const float pc  = r1 ? P[9] : P[4];
        const float pnc = r1 ? P[4] : P[9];
        const float contain = objf * (pc - max_iou) * (pc - max_iou);
        const float not_contain = objf * pnc * pnc;

        const float rx = r1 ? P[5] : P[0];
        const float ry = r1 ? P[6] : P[1];
        const float rw = r1 ? P[7] : P[2];
        const float rh = r1 ? P[8] : P[3];
        const float dx = rx - T[0];
        const float dy = ry - T[1];
        const float dw = sqrtf(rw) - sqrtf(T[2]);
        const float dh = sqrtf(rh) - sqrtf(T[3]);
        const float loc = objf * (dx * dx + dy * dy + dw * dw + dh * dh);

        float cls = 0.0f;
#pragma unroll
        for (int k = 10; k < 30; ++k) {
            const float d = P[k] - T[k];
            cls += d * d;
        }
        cls *= objf;

        acc += 5.0f * loc + 2.0f * contain + 0.5f * nooobj + cls + not_contain;
    }

    acc *= (1.0f / (float)N_BATCH);

    // wave reduction, then 4-wave block reduction -> one atomic per block
#pragma unroll
    for (int off = 32; off > 0; off >>= 1)
        acc += __shfl_down(acc, off, 64);

    __shared__ float wsum[BLOCK / 64];
    const int lane = threadIdx.x & 63;
    const int wid = (int)threadIdx.x >> 6;
    if (lane == 0) wsum[wid] = acc;
    __syncthreads();
    if (threadIdx.x == 0)
        atomicAdd(out, wsum[0] + wsum[1] + wsum[2] + wsum[3]);
}

extern "C" void kernel_launch(void* const* d_in, const int* in_sizes, int n_in,
                              void* d_out, int out_size, void* d_ws, size_t ws_size,
                              hipStream_t stream) {
    const float* pred = (const float*)d_in[0];
    const float* targ = (const float*)d_in[1];
    float* out = (float*)d_out;

    hipMemsetAsync(out, 0, sizeof(float), stream);

    yolo_loss_kernel<<<GRID, BLOCK, 0, stream>>>(pred, targ, out);
}